// Round 1
// baseline (3252.821 us; speedup 1.0000x reference)
//
#include <hip/hip_runtime.h>

// RotationLayer: out = x + scatter_add over edges of rotated neighbor vectors.
//   t_u = R(+phase) @ x[u]  accumulated into out[v]
//   t_v = R(-phase) @ x[v]  accumulated into out[u]

__global__ __launch_bounds__(256) void rot_init_out(const float* __restrict__ x,
                                                    float* __restrict__ out,
                                                    int n) {
    int i = blockIdx.x * blockDim.x + threadIdx.x;
    if (i < n) out[i] = x[i];
}

__global__ __launch_bounds__(256) void rot_edge_kernel(
    const float2* __restrict__ x2,
    const float* __restrict__ phases,
    const int2* __restrict__ edges,
    float* __restrict__ out,
    int n_edges)
{
    int e = blockIdx.x * blockDim.x + threadIdx.x;
    if (e >= n_edges) return;

    int2 uv = edges[e];          // 8B vector load
    int u = uv.x, v = uv.y;
    float p = phases[e];
    float s = __sinf(p);
    float c = __cosf(p);

    float2 hu = x2[u];           // gather, L2/L3-resident (x is 8 MB)
    float2 hv = x2[v];

    // t_u = R(+p) hu  -> out[v]
    float tux = hu.x * c - hu.y * s;
    float tuy = hu.x * s + hu.y * c;
    // t_v = R(-p) hv  -> out[u]
    float tvx = hv.x * c + hv.y * s;
    float tvy = hv.y * c - hv.x * s;

    // HW fp32 atomics (global_atomic_add_f32), device scope.
    unsafeAtomicAdd(&out[2 * v + 0], tux);
    unsafeAtomicAdd(&out[2 * v + 1], tuy);
    unsafeAtomicAdd(&out[2 * u + 0], tvx);
    unsafeAtomicAdd(&out[2 * u + 1], tvy);
}

extern "C" void kernel_launch(void* const* d_in, const int* in_sizes, int n_in,
                              void* d_out, int out_size, void* d_ws, size_t ws_size,
                              hipStream_t stream) {
    const float*  x      = (const float*)d_in[0];   // (1e6, 2) fp32
    const float*  phases = (const float*)d_in[1];   // (16e6,) fp32
    const int2*   edges  = (const int2*)d_in[2];    // (16e6, 2) int32
    float* out = (float*)d_out;                     // (1e6, 2) fp32

    const int n_out   = out_size;          // 2,000,000 floats
    const int n_edges = in_sizes[1];       // 16,000,000

    // Seed out = x (harness poisons d_out before every launch).
    {
        int block = 256;
        int grid = (n_out + block - 1) / block;
        rot_init_out<<<grid, block, 0, stream>>>(x, out, n_out);
    }
    // Edge scatter.
    {
        int block = 256;
        int grid = (n_edges + block - 1) / block;
        rot_edge_kernel<<<grid, block, 0, stream>>>(
            (const float2*)x, phases, edges, out, n_edges);
    }
}

// Round 2
// 1568.612 us; speedup vs baseline: 2.0737x; 2.0737x over previous
//
#include <hip/hip_runtime.h>
#include <hip/hip_fp16.h>
#include <math.h>

// RotationLayer: out = x + scatter_add over edges of rotated neighbor vectors.
//   t_u = R(+phase) @ x[u]  accumulated into out[v]
//   t_v = R(-phase) @ x[v]  accumulated into out[u]
//
// Strategy: global fp32 atomics cost ~48 B of memory-side traffic each
// (measured: WRITE_SIZE 32 B/atomic). Replace scatter-atomics with a
// 2-phase bucket pipeline: partition contributions into per-bucket record
// arrays in d_ws (one int atomic per block-bucket for slot reservation),
// then accumulate each bucket in fp32 LDS and write out = x + acc.

#define MAX_NB      1024      // LDS sizing; runtime nb must be <= this
#define NODE_SHIFT  10
#define BUCKET_NODES 1024
#define PART_BLOCK  256
#define EDGES_PER_THREAD 32
#define EDGES_PER_BLOCK (PART_BLOCK * EDGES_PER_THREAD)   // 8192

typedef unsigned int uint;

static __device__ __forceinline__ uint pack_half2(float a, float b) {
    __half2 h = __floats2half2_rn(a, b);
    union { __half2 h2; uint u; } cvt; cvt.h2 = h; return cvt.u;
}

__global__ __launch_bounds__(256) void rot_zero_cursors(uint* __restrict__ cursors, int nb) {
    int i = blockIdx.x * blockDim.x + threadIdx.x;
    if (i < nb) cursors[i] = 0u;
}

__global__ __launch_bounds__(PART_BLOCK) void rot_partition(
    const float2* __restrict__ x2,
    const float*  __restrict__ phases,
    const int2*   __restrict__ edges,
    uint*  __restrict__ cursors,
    uint2* __restrict__ records,
    int e_begin, int e_end, int cap, int nb)
{
    __shared__ uint s_hist[MAX_NB];
    __shared__ uint s_base[MAX_NB];

    for (int b = threadIdx.x; b < nb; b += PART_BLOCK) s_hist[b] = 0u;
    __syncthreads();

    const int block_e0 = e_begin + blockIdx.x * EDGES_PER_BLOCK;

    // Phase A: histogram of destination buckets (edges only; re-read in B hits L2)
    for (int i = 0; i < EDGES_PER_THREAD; ++i) {
        int e = block_e0 + i * PART_BLOCK + threadIdx.x;
        if (e < e_end) {
            int2 uv = edges[e];
            atomicAdd(&s_hist[(uint)uv.x >> NODE_SHIFT], 1u);
            atomicAdd(&s_hist[(uint)uv.y >> NODE_SHIFT], 1u);
        }
    }
    __syncthreads();

    // Reserve contiguous global slots: one global atomic per (block,bucket)
    for (int b = threadIdx.x; b < nb; b += PART_BLOCK) {
        uint c = s_hist[b];
        s_base[b] = c ? atomicAdd(&cursors[b], c) : 0u;
        s_hist[b] = 0u;   // reuse as intra-block cursor
    }
    __syncthreads();

    // Phase B: compute contributions and place records
    for (int i = 0; i < EDGES_PER_THREAD; ++i) {
        int e = block_e0 + i * PART_BLOCK + threadIdx.x;
        if (e < e_end) {
            int2 uv = edges[e];
            int u = uv.x, v = uv.y;
            float p = phases[e];
            float s, c;
            __sincosf(p, &s, &c);
            float2 hu = x2[u];
            float2 hv = x2[v];
            // contribution to out[v]: R(+p) @ hu
            float tux = hu.x * c - hu.y * s;
            float tuy = hu.x * s + hu.y * c;
            // contribution to out[u]: R(-p) @ hv
            float tvx = hv.x * c + hv.y * s;
            float tvy = hv.y * c - hv.x * s;

            {
                int b = (uint)v >> NODE_SHIFT;
                uint slot = s_base[b] + atomicAdd(&s_hist[b], 1u);
                records[(size_t)b * cap + slot] =
                    make_uint2((uint)v & (BUCKET_NODES - 1), pack_half2(tux, tuy));
            }
            {
                int b = (uint)u >> NODE_SHIFT;
                uint slot = s_base[b] + atomicAdd(&s_hist[b], 1u);
                records[(size_t)b * cap + slot] =
                    make_uint2((uint)u & (BUCKET_NODES - 1), pack_half2(tvx, tvy));
            }
        }
    }
}

__global__ __launch_bounds__(256) void rot_accumulate(
    const float* __restrict__ x,
    const uint*  __restrict__ cursors,
    const uint2* __restrict__ records,
    float* __restrict__ out,
    int cap, int n_nodes, int first_chunk)
{
    __shared__ float acc[BUCKET_NODES * 2];
    for (int i = threadIdx.x; i < BUCKET_NODES * 2; i += blockDim.x) acc[i] = 0.f;
    __syncthreads();

    const int b = blockIdx.x;
    uint cnt = cursors[b];
    if (cnt > (uint)cap) cnt = (uint)cap;   // paranoia clamp
    const uint2* rec = records + (size_t)b * cap;

    for (uint i = threadIdx.x; i < cnt; i += blockDim.x) {
        uint2 r = rec[i];
        union { uint u; __half2 h; } cvt; cvt.u = r.y;
        float2 f = __half22float2(cvt.h);
        atomicAdd(&acc[2u * r.x + 0u], f.x);
        atomicAdd(&acc[2u * r.x + 1u], f.y);
    }
    __syncthreads();

    const int node0 = b << NODE_SHIFT;
    const int lim = n_nodes * 2;
    for (int i = threadIdx.x; i < BUCKET_NODES * 2; i += blockDim.x) {
        int idx = node0 * 2 + i;
        if (idx < lim) {
            float base = first_chunk ? x[idx] : out[idx];
            out[idx] = base + acc[i];
        }
    }
}

// ---------------- fallback (round-1 atomic path, used only if ws too small) ---

__global__ __launch_bounds__(256) void rot_init_out(const float* __restrict__ x,
                                                    float* __restrict__ out, int n) {
    int i = blockIdx.x * blockDim.x + threadIdx.x;
    if (i < n) out[i] = x[i];
}

__global__ __launch_bounds__(256) void rot_edge_atomic(
    const float2* __restrict__ x2, const float* __restrict__ phases,
    const int2* __restrict__ edges, float* __restrict__ out, int n_edges)
{
    int e = blockIdx.x * blockDim.x + threadIdx.x;
    if (e >= n_edges) return;
    int2 uv = edges[e];
    float p = phases[e];
    float s = __sinf(p), c = __cosf(p);
    float2 hu = x2[uv.x], hv = x2[uv.y];
    unsafeAtomicAdd(&out[2 * uv.y + 0], hu.x * c - hu.y * s);
    unsafeAtomicAdd(&out[2 * uv.y + 1], hu.x * s + hu.y * c);
    unsafeAtomicAdd(&out[2 * uv.x + 0], hv.x * c + hv.y * s);
    unsafeAtomicAdd(&out[2 * uv.x + 1], hv.y * c - hv.x * s);
}

// -----------------------------------------------------------------------------

extern "C" void kernel_launch(void* const* d_in, const int* in_sizes, int n_in,
                              void* d_out, int out_size, void* d_ws, size_t ws_size,
                              hipStream_t stream) {
    const float* x      = (const float*)d_in[0];
    const float* phases = (const float*)d_in[1];
    const int2*  edges  = (const int2*)d_in[2];
    float* out = (float*)d_out;

    const int n_nodes = out_size / 2;
    const int E       = in_sizes[1];
    const int nb      = (n_nodes + BUCKET_NODES - 1) >> NODE_SHIFT;

    // Pick smallest chunk count k whose records fit in ws.
    int chosen_k = 0, chosen_cap = 0;
    if (d_ws && nb <= MAX_NB) {
        const int ks[5] = {1, 2, 4, 8, 16};
        for (int i = 0; i < 5; ++i) {
            int k = ks[i];
            long long e_chunk = ((long long)E + k - 1) / k;
            double m = (double)(2 * e_chunk) / (double)nb;
            long long cap = (long long)(m + 10.0 * sqrt(m) + 64.0);
            cap = (cap + 255) & ~255LL;
            long long need = (long long)nb * cap * 8 + (long long)nb * 4 + 256;
            if ((size_t)need <= ws_size) { chosen_k = k; chosen_cap = (int)cap; break; }
        }
    }

    if (chosen_k == 0) {
        // ws too small: atomic fallback
        rot_init_out<<<(out_size + 255) / 256, 256, 0, stream>>>(x, out, out_size);
        rot_edge_atomic<<<(E + 255) / 256, 256, 0, stream>>>(
            (const float2*)x, phases, edges, out, E);
        return;
    }

    const int cap = chosen_cap;
    uint2* records = (uint2*)d_ws;
    uint*  cursors = (uint*)((char*)d_ws + (size_t)nb * cap * 8);

    const int e_chunk = (E + chosen_k - 1) / chosen_k;
    for (int cidx = 0; cidx < chosen_k; ++cidx) {
        int e0 = cidx * e_chunk;
        int e1 = (e0 + e_chunk < E) ? (e0 + e_chunk) : E;
        if (e0 >= e1) break;

        rot_zero_cursors<<<(nb + 255) / 256, 256, 0, stream>>>(cursors, nb);

        int nblk = (e1 - e0 + EDGES_PER_BLOCK - 1) / EDGES_PER_BLOCK;
        rot_partition<<<nblk, PART_BLOCK, 0, stream>>>(
            (const float2*)x, phases, edges, cursors, records, e0, e1, cap, nb);

        rot_accumulate<<<nb, 256, 0, stream>>>(
            x, cursors, records, out, cap, n_nodes, cidx == 0 ? 1 : 0);
    }
}

// Round 3
// 941.724 us; speedup vs baseline: 3.4541x; 1.6657x over previous
//
#include <hip/hip_runtime.h>
#include <hip/hip_fp16.h>
#include <math.h>

// RotationLayer: out = x + scatter_add over edges of rotated neighbor vectors.
//   t_u = R(+phase) @ x[u]  accumulated into out[v]
//   t_v = R(-phase) @ x[v]  accumulated into out[u]
//
// Round-3 structure: block-local counting sort of records into LDS, then a
// contiguous coalesced flush (kills the 64B-line RFO penalty measured in
// round 2: 30 B write + ~32 B fetch per 8 B record). Edges held in VGPRs
// between histogram and placement (single edge read). Accumulate uses split
// accX/accY LDS (2-way bank aliasing = free) + uint4 record loads.

#define NODE_SHIFT   11
#define BUCKET_NODES 2048
#define MAX_NB       512      // >= ceil(n_nodes / BUCKET_NODES)
#define PART_BLOCK   256
#define EPT          8                       // edges per thread (in registers)
#define EPB          (PART_BLOCK * EPT)      // 2048 edges per block
#define RPB          (2 * EPB)               // 4096 records per block

typedef unsigned int uint;

static __device__ __forceinline__ uint pack_half2(float a, float b) {
    __half2 h = __floats2half2_rn(a, b);
    union { __half2 h2; uint u; } cvt; cvt.h2 = h; return cvt.u;
}

__global__ __launch_bounds__(256) void rot_zero_cursors(uint* __restrict__ cursors, int nb) {
    int i = blockIdx.x * blockDim.x + threadIdx.x;
    if (i < nb) cursors[i] = 0u;
}

__global__ __launch_bounds__(PART_BLOCK) void rot_partition(
    const float2* __restrict__ x2,
    const float*  __restrict__ phases,
    const int2*   __restrict__ edges,
    uint*  __restrict__ cursors,
    uint2* __restrict__ records,
    int e_begin, int e_end, int cap, int nbp)
{
    __shared__ uint2 s_rec[RPB];        // 32 KB sorted record staging
    __shared__ uint  s_cnt[MAX_NB];     // per-bucket counts
    __shared__ uint  s_scan[2][MAX_NB]; // Hillis-Steele ping-pong
    __shared__ uint  s_loc[MAX_NB];     // exclusive local offsets (preserved)
    __shared__ uint  s_cur[MAX_NB];     // placement cursors
    __shared__ uint  s_base[MAX_NB];    // global reserved bases

    const int tid = threadIdx.x;
    const int block_e0 = e_begin + blockIdx.x * EPB;

    // ---- 1. Load this thread's edges+phases into registers (coalesced) ----
    int2  ed[EPT];
    float ph[EPT];
    float2 hu[EPT], hv[EPT];
    #pragma unroll
    for (int i = 0; i < EPT; ++i) {
        int e = block_e0 + i * PART_BLOCK + tid;
        if (e < e_end) { ed[i] = edges[e]; ph[i] = phases[e]; }
        else           { ed[i] = make_int2(0, 0); ph[i] = 0.f; }
    }
    // ---- 2. Issue all gathers now; latency hides behind histogram+scan ----
    #pragma unroll
    for (int i = 0; i < EPT; ++i) {
        hu[i] = x2[ed[i].x];
        hv[i] = x2[ed[i].y];
    }

    // ---- 3. Histogram ----
    for (int b = tid; b < nbp; b += PART_BLOCK) s_cnt[b] = 0u;
    __syncthreads();
    #pragma unroll
    for (int i = 0; i < EPT; ++i) {
        int e = block_e0 + i * PART_BLOCK + tid;
        if (e < e_end) {
            atomicAdd(&s_cnt[(uint)ed[i].y >> NODE_SHIFT], 1u);
            atomicAdd(&s_cnt[(uint)ed[i].x >> NODE_SHIFT], 1u);
        }
    }
    __syncthreads();

    // ---- 4. Exclusive scan of counts (Hillis-Steele, double buffer) ----
    for (int b = tid; b < nbp; b += PART_BLOCK) s_scan[0][b] = s_cnt[b];
    __syncthreads();
    uint src = 0;
    for (uint off = 1; off < (uint)nbp; off <<= 1) {
        for (int b = tid; b < nbp; b += PART_BLOCK) {
            uint v = s_scan[src][b];
            if ((uint)b >= off) v += s_scan[src][b - off];
            s_scan[1 - src][b] = v;
        }
        __syncthreads();
        src = 1 - src;
    }
    // ---- 5. Local offsets + global reservation (1 atomic per bucket) ----
    for (int b = tid; b < nbp; b += PART_BLOCK) {
        uint excl = (b > 0) ? s_scan[src][b - 1] : 0u;
        s_loc[b] = excl;
        s_cur[b] = excl;
        uint c = s_cnt[b];
        s_base[b] = c ? atomicAdd(&cursors[b], c) : 0u;
    }
    __syncthreads();

    // ---- 6. Compute rotations, place records sorted-by-bucket in LDS ----
    #pragma unroll
    for (int i = 0; i < EPT; ++i) {
        int e = block_e0 + i * PART_BLOCK + tid;
        if (e < e_end) {
            int u = ed[i].x, v = ed[i].y;
            float s, c;
            __sincosf(ph[i], &s, &c);
            // contribution to out[v]: R(+p) @ x[u]
            float tux = hu[i].x * c - hu[i].y * s;
            float tuy = hu[i].x * s + hu[i].y * c;
            // contribution to out[u]: R(-p) @ x[v]
            float tvx = hv[i].x * c + hv[i].y * s;
            float tvy = hv[i].y * c - hv[i].x * s;
            {
                uint b = (uint)v >> NODE_SHIFT;
                uint slot = atomicAdd(&s_cur[b], 1u);
                s_rec[slot] = make_uint2((b << 16) | ((uint)v & (BUCKET_NODES - 1)),
                                         pack_half2(tux, tuy));
            }
            {
                uint b = (uint)u >> NODE_SHIFT;
                uint slot = atomicAdd(&s_cur[b], 1u);
                s_rec[slot] = make_uint2((b << 16) | ((uint)u & (BUCKET_NODES - 1)),
                                         pack_half2(tvx, tvy));
            }
        }
    }
    __syncthreads();

    // ---- 7. Coalesced flush: consecutive lanes -> consecutive global ----
    int valid_edges = e_end - block_e0;
    if (valid_edges > EPB) valid_edges = EPB;
    int total = 2 * valid_edges;
    for (int s = tid; s < total; s += PART_BLOCK) {
        uint2 r = s_rec[s];
        uint b = r.x >> 16;
        uint g = s_base[b] + ((uint)s - s_loc[b]);
        if (g < (uint)cap) records[(size_t)b * cap + g] = r;
    }
}

__global__ __launch_bounds__(256) void rot_accumulate(
    const float2* __restrict__ x2,
    const uint*   __restrict__ cursors,
    const uint2*  __restrict__ records,
    float2* __restrict__ out2,
    int cap, int n_nodes, int first_chunk)
{
    __shared__ float accX[BUCKET_NODES];
    __shared__ float accY[BUCKET_NODES];
    for (int i = threadIdx.x; i < BUCKET_NODES; i += blockDim.x) {
        accX[i] = 0.f; accY[i] = 0.f;
    }
    __syncthreads();

    const int b = blockIdx.x;
    uint cnt = cursors[b];
    if (cnt > (uint)cap) cnt = (uint)cap;
    const uint2* rec = records + (size_t)b * cap;

    // main loop: 2 records per 16B load (cap is 256-aligned so rec is 16B-aligned)
    const uint4* rec4 = (const uint4*)rec;
    uint n2 = cnt >> 1;
    for (uint i = threadIdx.x; i < n2; i += blockDim.x) {
        uint4 r = rec4[i];
        {
            union { uint u; __half2 h; } cvt; cvt.u = r.y;
            float2 f = __half22float2(cvt.h);
            uint node = r.x & 0xFFFFu;
            atomicAdd(&accX[node], f.x);
            atomicAdd(&accY[node], f.y);
        }
        {
            union { uint u; __half2 h; } cvt; cvt.u = r.w;
            float2 f = __half22float2(cvt.h);
            uint node = r.z & 0xFFFFu;
            atomicAdd(&accX[node], f.x);
            atomicAdd(&accY[node], f.y);
        }
    }
    if ((cnt & 1u) && threadIdx.x == 0) {
        uint2 r = rec[cnt - 1];
        union { uint u; __half2 h; } cvt; cvt.u = r.y;
        float2 f = __half22float2(cvt.h);
        uint node = r.x & 0xFFFFu;
        atomicAdd(&accX[node], f.x);
        atomicAdd(&accY[node], f.y);
    }
    __syncthreads();

    const int node0 = b << NODE_SHIFT;
    for (int i = threadIdx.x; i < BUCKET_NODES; i += blockDim.x) {
        int node = node0 + i;
        if (node < n_nodes) {
            float2 base = first_chunk ? x2[node] : out2[node];
            out2[node] = make_float2(base.x + accX[i], base.y + accY[i]);
        }
    }
}

// ---------------- fallback (atomic path, used only if ws too small) ----------

__global__ __launch_bounds__(256) void rot_init_out(const float* __restrict__ x,
                                                    float* __restrict__ out, int n) {
    int i = blockIdx.x * blockDim.x + threadIdx.x;
    if (i < n) out[i] = x[i];
}

__global__ __launch_bounds__(256) void rot_edge_atomic(
    const float2* __restrict__ x2, const float* __restrict__ phases,
    const int2* __restrict__ edges, float* __restrict__ out, int n_edges)
{
    int e = blockIdx.x * blockDim.x + threadIdx.x;
    if (e >= n_edges) return;
    int2 uv = edges[e];
    float p = phases[e];
    float s = __sinf(p), c = __cosf(p);
    float2 hu = x2[uv.x], hv = x2[uv.y];
    unsafeAtomicAdd(&out[2 * uv.y + 0], hu.x * c - hu.y * s);
    unsafeAtomicAdd(&out[2 * uv.y + 1], hu.x * s + hu.y * c);
    unsafeAtomicAdd(&out[2 * uv.x + 0], hv.x * c + hv.y * s);
    unsafeAtomicAdd(&out[2 * uv.x + 1], hv.y * c - hv.x * s);
}

// -----------------------------------------------------------------------------

extern "C" void kernel_launch(void* const* d_in, const int* in_sizes, int n_in,
                              void* d_out, int out_size, void* d_ws, size_t ws_size,
                              hipStream_t stream) {
    const float* x      = (const float*)d_in[0];
    const float* phases = (const float*)d_in[1];
    const int2*  edges  = (const int2*)d_in[2];
    float* out = (float*)d_out;

    const int n_nodes = out_size / 2;
    const int E       = in_sizes[1];
    const int nb      = (n_nodes + BUCKET_NODES - 1) >> NODE_SHIFT;

    // Pick smallest chunk count k whose records fit in ws.
    int chosen_k = 0, chosen_cap = 0;
    if (d_ws && nb <= MAX_NB) {
        const int ks[5] = {1, 2, 4, 8, 16};
        for (int i = 0; i < 5; ++i) {
            int k = ks[i];
            long long e_chunk = ((long long)E + k - 1) / k;
            double m = (double)(2 * e_chunk) / (double)nb;
            long long cap = (long long)(m + 10.0 * sqrt(m) + 64.0);
            cap = (cap + 255) & ~255LL;
            long long need = (long long)nb * cap * 8 + (long long)nb * 4 + 256;
            if ((size_t)need <= ws_size) { chosen_k = k; chosen_cap = (int)cap; break; }
        }
    }

    if (chosen_k == 0) {
        rot_init_out<<<(out_size + 255) / 256, 256, 0, stream>>>(x, out, out_size);
        rot_edge_atomic<<<(E + 255) / 256, 256, 0, stream>>>(
            (const float2*)x, phases, edges, out, E);
        return;
    }

    const int cap = chosen_cap;
    uint2* records = (uint2*)d_ws;
    uint*  cursors = (uint*)((char*)d_ws + (size_t)nb * cap * 8);

    const int e_chunk = (E + chosen_k - 1) / chosen_k;
    for (int cidx = 0; cidx < chosen_k; ++cidx) {
        int e0 = cidx * e_chunk;
        int e1 = (e0 + e_chunk < E) ? (e0 + e_chunk) : E;
        if (e0 >= e1) break;

        rot_zero_cursors<<<(nb + 255) / 256, 256, 0, stream>>>(cursors, nb);

        int nblk = (e1 - e0 + EPB - 1) / EPB;
        rot_partition<<<nblk, PART_BLOCK, 0, stream>>>(
            (const float2*)x, phases, edges, cursors, records, e0, e1, cap, nb);

        rot_accumulate<<<nb, 256, 0, stream>>>(
            (const float2*)x, cursors, records, (float2*)out, cap, n_nodes,
            cidx == 0 ? 1 : 0);
    }
}

// Round 4
// 557.602 us; speedup vs baseline: 5.8336x; 1.6889x over previous
//
#include <hip/hip_runtime.h>
#include <hip/hip_fp16.h>
#include <math.h>

// RotationLayer: out = x + scatter_add over edges of rotated neighbor vectors.
//   t_u = R(+phase) @ x[u]  accumulated into out[v]
//   t_v = R(-phase) @ x[v]  accumulated into out[u]
//
// Round 4:
//  - accumulate: LDS float atomicAdd was the bottleneck (CAS-loop lowering);
//    switched to native integer ds_add with 2^16 fixed-point. 512-thr blocks,
//    2x unrolled uint4 record loads.
//  - partition: x gathered from a 4 MB half2 table in ws (fits per-XCD L2)
//    instead of the 8 MB float2 table (~50% L2 miss -> ~1 GB excess fetch).

#define NODE_SHIFT   11
#define BUCKET_NODES 2048
#define MAX_NB       512
#define PART_BLOCK   256
#define EPT          8                       // edges per thread (in registers)
#define EPB          (PART_BLOCK * EPT)      // 2048 edges per block
#define RPB          (2 * EPB)               // 4096 records per block

#define ACC_BLOCK    512
#define FIX_SCALE    65536.0f
#define INV_FIX      (1.0f / 65536.0f)

typedef unsigned int uint;

static __device__ __forceinline__ uint pack_half2(float a, float b) {
    __half2 h = __floats2half2_rn(a, b);
    union { __half2 h2; uint u; } cvt; cvt.h2 = h; return cvt.u;
}

__global__ __launch_bounds__(256) void rot_make_xh(const float2* __restrict__ x2,
                                                   __half2* __restrict__ xh, int n) {
    int i = blockIdx.x * blockDim.x + threadIdx.x;
    if (i < n) {
        float2 v = x2[i];
        xh[i] = __floats2half2_rn(v.x, v.y);
    }
}

__global__ __launch_bounds__(256) void rot_zero_cursors(uint* __restrict__ cursors, int nb) {
    int i = blockIdx.x * blockDim.x + threadIdx.x;
    if (i < nb) cursors[i] = 0u;
}

__global__ __launch_bounds__(PART_BLOCK) void rot_partition(
    const __half2* __restrict__ xh,
    const float*  __restrict__ phases,
    const int2*   __restrict__ edges,
    uint*  __restrict__ cursors,
    uint2* __restrict__ records,
    int e_begin, int e_end, int cap, int nbp)
{
    __shared__ uint2 s_rec[RPB];        // 32 KB sorted record staging
    __shared__ uint  s_cnt[MAX_NB];
    __shared__ uint  s_scan[2][MAX_NB];
    __shared__ uint  s_loc[MAX_NB];
    __shared__ uint  s_cur[MAX_NB];
    __shared__ uint  s_base[MAX_NB];

    const int tid = threadIdx.x;
    const int block_e0 = e_begin + blockIdx.x * EPB;

    // ---- 1. Load this thread's edges+phases into registers (coalesced) ----
    int2  ed[EPT];
    float ph[EPT];
    __half2 hu[EPT], hv[EPT];
    #pragma unroll
    for (int i = 0; i < EPT; ++i) {
        int e = block_e0 + i * PART_BLOCK + tid;
        if (e < e_end) { ed[i] = edges[e]; ph[i] = phases[e]; }
        else           { ed[i] = make_int2(0, 0); ph[i] = 0.f; }
    }
    // ---- 2. Issue all gathers now; latency hides behind histogram+scan ----
    #pragma unroll
    for (int i = 0; i < EPT; ++i) {
        hu[i] = xh[ed[i].x];
        hv[i] = xh[ed[i].y];
    }

    // ---- 3. Histogram ----
    for (int b = tid; b < nbp; b += PART_BLOCK) s_cnt[b] = 0u;
    __syncthreads();
    #pragma unroll
    for (int i = 0; i < EPT; ++i) {
        int e = block_e0 + i * PART_BLOCK + tid;
        if (e < e_end) {
            atomicAdd(&s_cnt[(uint)ed[i].y >> NODE_SHIFT], 1u);
            atomicAdd(&s_cnt[(uint)ed[i].x >> NODE_SHIFT], 1u);
        }
    }
    __syncthreads();

    // ---- 4. Exclusive scan of counts ----
    for (int b = tid; b < nbp; b += PART_BLOCK) s_scan[0][b] = s_cnt[b];
    __syncthreads();
    uint src = 0;
    for (uint off = 1; off < (uint)nbp; off <<= 1) {
        for (int b = tid; b < nbp; b += PART_BLOCK) {
            uint v = s_scan[src][b];
            if ((uint)b >= off) v += s_scan[src][b - off];
            s_scan[1 - src][b] = v;
        }
        __syncthreads();
        src = 1 - src;
    }
    // ---- 5. Local offsets + global reservation (1 atomic per bucket) ----
    for (int b = tid; b < nbp; b += PART_BLOCK) {
        uint excl = (b > 0) ? s_scan[src][b - 1] : 0u;
        s_loc[b] = excl;
        s_cur[b] = excl;
        uint c = s_cnt[b];
        s_base[b] = c ? atomicAdd(&cursors[b], c) : 0u;
    }
    __syncthreads();

    // ---- 6. Compute rotations, place records sorted-by-bucket in LDS ----
    #pragma unroll
    for (int i = 0; i < EPT; ++i) {
        int e = block_e0 + i * PART_BLOCK + tid;
        if (e < e_end) {
            int u = ed[i].x, v = ed[i].y;
            float s, c;
            __sincosf(ph[i], &s, &c);
            float2 fu = __half22float2(hu[i]);
            float2 fv = __half22float2(hv[i]);
            // contribution to out[v]: R(+p) @ x[u]
            float tux = fu.x * c - fu.y * s;
            float tuy = fu.x * s + fu.y * c;
            // contribution to out[u]: R(-p) @ x[v]
            float tvx = fv.x * c + fv.y * s;
            float tvy = fv.y * c - fv.x * s;
            {
                uint b = (uint)v >> NODE_SHIFT;
                uint slot = atomicAdd(&s_cur[b], 1u);
                s_rec[slot] = make_uint2((b << 16) | ((uint)v & (BUCKET_NODES - 1)),
                                         pack_half2(tux, tuy));
            }
            {
                uint b = (uint)u >> NODE_SHIFT;
                uint slot = atomicAdd(&s_cur[b], 1u);
                s_rec[slot] = make_uint2((b << 16) | ((uint)u & (BUCKET_NODES - 1)),
                                         pack_half2(tvx, tvy));
            }
        }
    }
    __syncthreads();

    // ---- 7. Coalesced flush ----
    int valid_edges = e_end - block_e0;
    if (valid_edges > EPB) valid_edges = EPB;
    int total = 2 * valid_edges;
    for (int s = tid; s < total; s += PART_BLOCK) {
        uint2 r = s_rec[s];
        uint b = r.x >> 16;
        uint g = s_base[b] + ((uint)s - s_loc[b]);
        if (g < (uint)cap) records[(size_t)b * cap + g] = r;
    }
}

static __device__ __forceinline__ void acc_record(int* accX, int* accY, uint key, uint payload) {
    union { uint u; __half2 h; } cvt; cvt.u = payload;
    float2 f = __half22float2(cvt.h);
    uint node = key & 0xFFFFu;
    atomicAdd(&accX[node], __float2int_rn(f.x * FIX_SCALE));
    atomicAdd(&accY[node], __float2int_rn(f.y * FIX_SCALE));
}

__global__ __launch_bounds__(ACC_BLOCK) void rot_accumulate(
    const float2* __restrict__ x2,
    const uint*   __restrict__ cursors,
    const uint2*  __restrict__ records,
    float2* __restrict__ out2,
    int cap, int n_nodes, int first_chunk)
{
    __shared__ int accX[BUCKET_NODES];
    __shared__ int accY[BUCKET_NODES];
    for (int i = threadIdx.x; i < BUCKET_NODES; i += ACC_BLOCK) {
        accX[i] = 0; accY[i] = 0;
    }
    __syncthreads();

    const int b = blockIdx.x;
    uint cnt = cursors[b];
    if (cnt > (uint)cap) cnt = (uint)cap;
    const uint2* rec = records + (size_t)b * cap;

    // 2x-unrolled uint4 loads (4 records per iteration per thread)
    const uint4* rec4 = (const uint4*)rec;
    uint n4 = cnt >> 1;                     // number of uint4 elements
    uint tid = threadIdx.x;
    for (uint i = tid; i < n4; i += 2u * ACC_BLOCK) {
        uint4 r0 = rec4[i];
        bool has1 = (i + ACC_BLOCK) < n4;
        uint4 r1 = has1 ? rec4[i + ACC_BLOCK] : make_uint4(0, 0, 0, 0);
        acc_record(accX, accY, r0.x, r0.y);
        acc_record(accX, accY, r0.z, r0.w);
        if (has1) {
            acc_record(accX, accY, r1.x, r1.y);
            acc_record(accX, accY, r1.z, r1.w);
        }
    }
    if ((cnt & 1u) && tid == 0) {
        uint2 r = rec[cnt - 1];
        acc_record(accX, accY, r.x, r.y);
    }
    __syncthreads();

    const int node0 = b << NODE_SHIFT;
    for (int i = threadIdx.x; i < BUCKET_NODES; i += ACC_BLOCK) {
        int node = node0 + i;
        if (node < n_nodes) {
            float ax = (float)accX[i] * INV_FIX;
            float ay = (float)accY[i] * INV_FIX;
            float2 base = first_chunk ? x2[node] : out2[node];
            out2[node] = make_float2(base.x + ax, base.y + ay);
        }
    }
}

// ---------------- fallback (atomic path, used only if ws too small) ----------

__global__ __launch_bounds__(256) void rot_init_out(const float* __restrict__ x,
                                                    float* __restrict__ out, int n) {
    int i = blockIdx.x * blockDim.x + threadIdx.x;
    if (i < n) out[i] = x[i];
}

__global__ __launch_bounds__(256) void rot_edge_atomic(
    const float2* __restrict__ x2, const float* __restrict__ phases,
    const int2* __restrict__ edges, float* __restrict__ out, int n_edges)
{
    int e = blockIdx.x * blockDim.x + threadIdx.x;
    if (e >= n_edges) return;
    int2 uv = edges[e];
    float p = phases[e];
    float s = __sinf(p), c = __cosf(p);
    float2 hu = x2[uv.x], hv = x2[uv.y];
    unsafeAtomicAdd(&out[2 * uv.y + 0], hu.x * c - hu.y * s);
    unsafeAtomicAdd(&out[2 * uv.y + 1], hu.x * s + hu.y * c);
    unsafeAtomicAdd(&out[2 * uv.x + 0], hv.x * c + hv.y * s);
    unsafeAtomicAdd(&out[2 * uv.x + 1], hv.y * c - hv.x * s);
}

// -----------------------------------------------------------------------------

extern "C" void kernel_launch(void* const* d_in, const int* in_sizes, int n_in,
                              void* d_out, int out_size, void* d_ws, size_t ws_size,
                              hipStream_t stream) {
    const float* x      = (const float*)d_in[0];
    const float* phases = (const float*)d_in[1];
    const int2*  edges  = (const int2*)d_in[2];
    float* out = (float*)d_out;

    const int n_nodes = out_size / 2;
    const int E       = in_sizes[1];
    const int nb      = (n_nodes + BUCKET_NODES - 1) >> NODE_SHIFT;

    // Pick smallest chunk count k whose records + cursors + xh table fit in ws.
    int chosen_k = 0, chosen_cap = 0;
    if (d_ws && nb <= MAX_NB) {
        const int ks[5] = {1, 2, 4, 8, 16};
        for (int i = 0; i < 5; ++i) {
            int k = ks[i];
            long long e_chunk = ((long long)E + k - 1) / k;
            double m = (double)(2 * e_chunk) / (double)nb;
            long long cap = (long long)(m + 10.0 * sqrt(m) + 64.0);
            cap = (cap + 255) & ~255LL;
            long long need = (long long)nb * cap * 8       // records
                           + (((long long)nb * 4 + 255) & ~255LL)  // cursors
                           + (long long)n_nodes * 4 + 512;         // xh table
            if ((size_t)need <= ws_size) { chosen_k = k; chosen_cap = (int)cap; break; }
        }
    }

    if (chosen_k == 0) {
        rot_init_out<<<(out_size + 255) / 256, 256, 0, stream>>>(x, out, out_size);
        rot_edge_atomic<<<(E + 255) / 256, 256, 0, stream>>>(
            (const float2*)x, phases, edges, out, E);
        return;
    }

    const int cap = chosen_cap;
    uint2*   records = (uint2*)d_ws;
    size_t   off = (size_t)nb * cap * 8;
    uint*    cursors = (uint*)((char*)d_ws + off);
    off += ((size_t)nb * 4 + 255) & ~(size_t)255;
    __half2* xh = (__half2*)((char*)d_ws + off);

    // Build the 4 MB half2 gather table (fits per-XCD L2).
    rot_make_xh<<<(n_nodes + 255) / 256, 256, 0, stream>>>((const float2*)x, xh, n_nodes);

    const int e_chunk = (E + chosen_k - 1) / chosen_k;
    for (int cidx = 0; cidx < chosen_k; ++cidx) {
        int e0 = cidx * e_chunk;
        int e1 = (e0 + e_chunk < E) ? (e0 + e_chunk) : E;
        if (e0 >= e1) break;

        rot_zero_cursors<<<(nb + 255) / 256, 256, 0, stream>>>(cursors, nb);

        int nblk = (e1 - e0 + EPB - 1) / EPB;
        rot_partition<<<nblk, PART_BLOCK, 0, stream>>>(
            xh, phases, edges, cursors, records, e0, e1, cap, nb);

        rot_accumulate<<<nb, ACC_BLOCK, 0, stream>>>(
            (const float2*)x, cursors, records, (float2*)out, cap, n_nodes,
            cidx == 0 ? 1 : 0);
    }
}